// Round 1
// baseline (242.222 us; speedup 1.0000x reference)
//
#include <hip/hip_runtime.h>
#include <stdint.h>

#define TSEQ 4096
#define DM   1024
#define NH   16
#define HD   64
#define NQKV 3072

typedef unsigned short u16;
typedef unsigned int   u32;
typedef __attribute__((ext_vector_type(8))) short bf16x8;
typedef __attribute__((ext_vector_type(4))) float f32x4;
typedef __attribute__((ext_vector_type(4))) int   i32x4;

static __device__ __forceinline__ u16 f2bf(float f) {
  u32 u = __float_as_uint(f);
  u32 r = (u + 0x7FFFu + ((u >> 16) & 1u)) >> 16;   // RNE
  return (u16)r;
}
static __device__ __forceinline__ float bf2f(u16 u) {
  return __uint_as_float(((u32)u) << 16);
}

#define GLL16(g, l) __builtin_amdgcn_global_load_lds( \
    (const __attribute__((address_space(1))) u32*)(g), \
    (__attribute__((address_space(3))) u32*)(l), 16, 0, 0)

// ---------------- cast fp32 -> bf16 (4 elems/thread) ----------------
__global__ void cast_kernel(const float* __restrict__ in, u16* __restrict__ out, int n4) {
  int i = blockIdx.x * 256 + threadIdx.x;
  if (i >= n4) return;
  float4 v = ((const float4*)in)[i];
  ushort4 o;
  o.x = f2bf(v.x); o.y = f2bf(v.y); o.z = f2bf(v.z); o.w = f2bf(v.w);
  ((ushort4*)out)[i] = o;
}

// ---------------- RoPE sin/cos table [T][32] ----------------
__global__ void rope_table(float* __restrict__ sT, float* __restrict__ cT) {
  int i = blockIdx.x * 256 + threadIdx.x;   // t*32 + j
  int t = i >> 5, j = i & 31;
  float inv = exp2f((float)j * (-13.287712379549449f / 32.0f)); // 10000^(-j/32)
  float ang = (float)t * inv;
  sT[i] = sinf(ang);
  cT[i] = cosf(ang);
}

// ---------------- GEMM C[M,N] = A[M,K] * B[N,K]^T (bf16 in, fp32 acc) --------
// m97 structure: 128x128 tile, BK=32, 4 waves (2x2 of 64x64), global_load_lds w=16
template<int WRITE_BF16>
__global__ __launch_bounds__(256) void gemm_bt(const u16* __restrict__ A,
                                               const u16* __restrict__ B,
                                               void* __restrict__ Cout,
                                               int M, int N, int K)
{
  __shared__ __align__(16) u16 As[128 * 32];
  __shared__ __align__(16) u16 Bs[128 * 32];
  const int tid  = threadIdx.x;
  const int wave = tid >> 6, lane = tid & 63;
  const int l15  = lane & 15, lh = lane >> 4;
  const int wr   = wave >> 1, wc = wave & 1;
  const size_t bm = blockIdx.y, bn = blockIdx.x;

  f32x4 acc[4][4] = {};

  const u16* Ab = A + bm * 128 * (size_t)K;
  const u16* Bb = B + bn * 128 * (size_t)K;

  for (int k0 = 0; k0 < K; k0 += 32) {
    __syncthreads();
#pragma unroll
    for (int j = 0; j < 2; ++j) {
      const int ch = j * 4 + wave;            // 8 chunks of 1024B per tile
      const int e  = ch * 512 + lane * 8;     // element within tile (row-major [128][32])
      const int r  = e >> 5, c = e & 31;
      GLL16(Ab + (size_t)r * K + k0 + c, As + ch * 512);
      GLL16(Bb + (size_t)r * K + k0 + c, Bs + ch * 512);
    }
    asm volatile("s_waitcnt vmcnt(0)" ::: "memory");
    __syncthreads();

    bf16x8 af[4], bfr[4];
#pragma unroll
    for (int m = 0; m < 4; ++m)
      af[m] = *(const bf16x8*)(As + (wr * 64 + m * 16 + l15) * 32 + lh * 8);
#pragma unroll
    for (int n = 0; n < 4; ++n)
      bfr[n] = *(const bf16x8*)(Bs + (wc * 64 + n * 16 + l15) * 32 + lh * 8);
#pragma unroll
    for (int m = 0; m < 4; ++m)
#pragma unroll
      for (int n = 0; n < 4; ++n)
        acc[m][n] = __builtin_amdgcn_mfma_f32_16x16x32_bf16(af[m], bfr[n], acc[m][n], 0, 0, 0);
  }

#pragma unroll
  for (int m = 0; m < 4; ++m)
#pragma unroll
    for (int n = 0; n < 4; ++n)
#pragma unroll
      for (int r = 0; r < 4; ++r) {
        size_t row = bm * 128 + wr * 64 + m * 16 + lh * 4 + r;
        size_t col = bn * 128 + wc * 64 + n * 16 + l15;
        float v = acc[m][n][r];
        if (WRITE_BF16) ((u16*)Cout)[row * N + col] = f2bf(v);
        else            ((float*)Cout)[row * N + col] = v;
      }
}

// ---------------- RoPE + head-split + V transpose ----------------
// qkv [T][3072] bf16 -> Q[H][T][64] (roped, *0.125), K[H][T][64] (roped), Vt[H][64][T]
__global__ void rope_reorg(const u16* __restrict__ qkv,
                           const float* __restrict__ sT, const float* __restrict__ cT,
                           u16* __restrict__ Qo, u16* __restrict__ Ko, u16* __restrict__ Vo)
{
  int idx = blockIdx.x * 256 + threadIdx.x;   // (t*16 + h)*32 + j
  int j = idx & 31;
  int h = (idx >> 5) & 15;
  int t = idx >> 9;
  float s = sT[t * 32 + j], c = cT[t * 32 + j];
  const u16* row = qkv + (size_t)t * NQKV + h * HD;
  float q1 = bf2f(row[j]),          q2 = bf2f(row[j + 32]);
  float k1 = bf2f(row[DM + j]),     k2 = bf2f(row[DM + j + 32]);
  size_t b = ((size_t)h * TSEQ + t) * HD;
  Qo[b + j]      = f2bf((q1 * c - q2 * s) * 0.125f);
  Qo[b + j + 32] = f2bf((q2 * c + q1 * s) * 0.125f);
  Ko[b + j]      = f2bf(k1 * c - k2 * s);
  Ko[b + j + 32] = f2bf(k2 * c + k1 * s);
  Vo[((size_t)h * HD + j) * TSEQ + t]      = row[2 * DM + j];
  Vo[((size_t)h * HD + j + 32) * TSEQ + t] = row[2 * DM + j + 32];
}

// ---------------- causal flash attention ----------------
// grid: 16 heads x 64 q-tiles (big q-tiles dispatched first). 4 waves x 16 q rows.
__global__ __launch_bounds__(256) void fattn(const u16* __restrict__ Q,
                                             const u16* __restrict__ Kk,
                                             const u16* __restrict__ Vt,
                                             u16* __restrict__ Oa)
{
  __shared__ __align__(16) u16 Ks[64 * 64];
  __shared__ __align__(16) u16 Vs[64 * 64];
  __shared__ __align__(16) u16 Ps[4 * 16 * 64];

  const int h  = blockIdx.x & (NH - 1);
  const int qt = (TSEQ / 64 - 1) - (blockIdx.x >> 4);
  const int q0 = qt * 64;
  const int tid = threadIdx.x;
  const int wave = tid >> 6, lane = tid & 63;
  const int l15 = lane & 15, lh = lane >> 4;

  bf16x8 qf0, qf1;
  {
    const u16* qp = Q + ((size_t)h * TSEQ + q0 + wave * 16 + l15) * HD + lh * 8;
    qf0 = *(const bf16x8*)(qp);
    qf1 = *(const bf16x8*)(qp + 32);
  }
  f32x4 oacc[4] = {};
  float mrun[4], lrun[4];
#pragma unroll
  for (int r = 0; r < 4; ++r) { mrun[r] = -3.0e38f; lrun[r] = 0.f; }

  const int nkv = qt + 1;
  for (int kt = 0; kt < nkv; ++kt) {
    const int kv0 = kt * 64;
    __syncthreads();   // protect LDS from previous iteration's reads
    // stage K tile [64 t][64 d] and V^T tile [64 d][64 t], XOR-swizzled 16B blocks
#pragma unroll
    for (int cc = 0; cc < 2; ++cc) {
      int c = tid + cc * 256;
      int row = c >> 3, cb = c & 7;
      i32x4 kv = *(const i32x4*)(Kk + ((size_t)h * TSEQ + kv0 + row) * HD + cb * 8);
      *(i32x4*)(Ks + row * 64 + ((cb ^ (row & 7)) * 8)) = kv;
      i32x4 vv = *(const i32x4*)(Vt + ((size_t)h * HD + row) * TSEQ + kv0 + cb * 8);
      *(i32x4*)(Vs + row * 64 + ((cb ^ (row & 7)) * 8)) = vv;
    }
    __syncthreads();

    // S = Q K^T  (A = Q strip [16x64], B = K^T [64x64] in 4 col-tiles)
    f32x4 sacc[4];
#pragma unroll
    for (int n = 0; n < 4; ++n) {
      int krow = n * 16 + l15;
      bf16x8 kf0 = *(const bf16x8*)(Ks + krow * 64 + ((lh       ^ (krow & 7)) * 8));
      bf16x8 kf1 = *(const bf16x8*)(Ks + krow * 64 + (((4 + lh) ^ (krow & 7)) * 8));
      f32x4 z = {0.f, 0.f, 0.f, 0.f};
      sacc[n] = __builtin_amdgcn_mfma_f32_16x16x32_bf16(qf0, kf0, z, 0, 0, 0);
      sacc[n] = __builtin_amdgcn_mfma_f32_16x16x32_bf16(qf1, kf1, sacc[n], 0, 0, 0);
    }

    const bool diag = (kv0 == q0);
#pragma unroll
    for (int r = 0; r < 4; ++r) {
      const int qrow = q0 + wave * 16 + lh * 4 + r;
      if (diag) {
#pragma unroll
        for (int n = 0; n < 4; ++n) {
          int col = kv0 + n * 16 + l15;
          if (col > qrow) sacc[n][r] = -3.0e38f;
        }
      }
      float tm = fmaxf(fmaxf(sacc[0][r], sacc[1][r]), fmaxf(sacc[2][r], sacc[3][r]));
      tm = fmaxf(tm, __shfl_xor(tm, 1));
      tm = fmaxf(tm, __shfl_xor(tm, 2));
      tm = fmaxf(tm, __shfl_xor(tm, 4));
      tm = fmaxf(tm, __shfl_xor(tm, 8));
      float nm = fmaxf(mrun[r], tm);
      float sf = __expf(mrun[r] - nm);
      float rs = 0.f;
      const int prow = lh * 4 + r;
#pragma unroll
      for (int n = 0; n < 4; ++n) {
        float p = __expf(sacc[n][r] - nm);
        rs += p;
        int pcol = n * 16 + l15;
        int cb = pcol >> 3, ci = pcol & 7;
        Ps[wave * 1024 + prow * 64 + ((cb ^ (prow & 7)) * 8) + ci] = f2bf(p);
      }
      rs += __shfl_xor(rs, 1);
      rs += __shfl_xor(rs, 2);
      rs += __shfl_xor(rs, 4);
      rs += __shfl_xor(rs, 8);
      lrun[r] = lrun[r] * sf + rs;
      mrun[r] = nm;
#pragma unroll
      for (int dn = 0; dn < 4; ++dn) oacc[dn][r] *= sf;
    }
    __syncthreads();   // P visible to own wave (lgkm drained), K reads complete

    // O += P * V   (A = P [16x64], B = V [64 kv x 64 d] from Vt tile)
#pragma unroll
    for (int kk = 0; kk < 2; ++kk) {
      bf16x8 pf = *(const bf16x8*)(Ps + wave * 1024 + l15 * 64 + (((kk * 4 + lh) ^ (l15 & 7)) * 8));
#pragma unroll
      for (int dn = 0; dn < 4; ++dn) {
        int vrow = dn * 16 + l15;
        bf16x8 vf = *(const bf16x8*)(Vs + vrow * 64 + (((kk * 4 + lh) ^ (vrow & 7)) * 8));
        oacc[dn] = __builtin_amdgcn_mfma_f32_16x16x32_bf16(pf, vf, oacc[dn], 0, 0, 0);
      }
    }
  }

#pragma unroll
  for (int r = 0; r < 4; ++r) {
    float inv = 1.f / lrun[r];
    size_t row = q0 + wave * 16 + lh * 4 + r;
#pragma unroll
    for (int dn = 0; dn < 4; ++dn)
      Oa[row * DM + h * HD + dn * 16 + l15] = f2bf(oacc[dn][r] * inv);
  }
}

extern "C" void kernel_launch(void* const* d_in, const int* in_sizes, int n_in,
                              void* d_out, int out_size, void* d_ws, size_t ws_size,
                              hipStream_t stream)
{
  const float* x     = (const float*)d_in[0];
  const float* wqkv  = (const float*)d_in[1];
  const float* wproj = (const float*)d_in[2];
  float* out = (float*)d_out;

  char* ws = (char*)d_ws;
  size_t off = 0;
  u16* xb   = (u16*)(ws + off); off += (size_t)TSEQ * DM * 2;
  u16* wqb  = (u16*)(ws + off); off += (size_t)NQKV * DM * 2;
  u16* wpb  = (u16*)(ws + off); off += (size_t)DM * DM * 2;
  u16* qkvb = (u16*)(ws + off); off += (size_t)TSEQ * NQKV * 2;
  u16* Qb   = (u16*)(ws + off); off += (size_t)NH * TSEQ * HD * 2;
  u16* Kb   = (u16*)(ws + off); off += (size_t)NH * TSEQ * HD * 2;
  u16* Vb   = (u16*)(ws + off); off += (size_t)NH * TSEQ * HD * 2;
  u16* Ob   = (u16*)(ws + off); off += (size_t)TSEQ * DM * 2;
  float* sT = (float*)(ws + off); off += (size_t)TSEQ * 32 * 4;
  float* cT = (float*)(ws + off); off += (size_t)TSEQ * 32 * 4;

  cast_kernel<<<(TSEQ * DM / 4) / 256, 256, 0, stream>>>(x, xb, TSEQ * DM / 4);
  cast_kernel<<<(NQKV * DM / 4) / 256, 256, 0, stream>>>(wqkv, wqb, NQKV * DM / 4);
  cast_kernel<<<(DM * DM / 4) / 256, 256, 0, stream>>>(wproj, wpb, DM * DM / 4);
  rope_table<<<(TSEQ * 32) / 256, 256, 0, stream>>>(sT, cT);

  gemm_bt<1><<<dim3(NQKV / 128, TSEQ / 128), 256, 0, stream>>>(xb, wqb, qkvb, TSEQ, NQKV, DM);

  rope_reorg<<<(TSEQ * NH * 32) / 256, 256, 0, stream>>>(qkvb, sT, cT, Qb, Kb, Vb);

  fattn<<<NH * (TSEQ / 64), 256, 0, stream>>>(Qb, Kb, Vb, Ob);

  gemm_bt<0><<<dim3(DM / 128, TSEQ / 128), 256, 0, stream>>>(Ob, wpb, out, TSEQ, DM, DM);
}

// Round 2
// 203.918 us; speedup vs baseline: 1.1878x; 1.1878x over previous
//
#include <hip/hip_runtime.h>
#include <hip/hip_bf16.h>
#include <stdint.h>

#define TSEQ 4096
#define DM   1024
#define NH   16
#define HD   64
#define NQKV 3072

typedef unsigned short u16;
typedef unsigned int   u32;
typedef __attribute__((ext_vector_type(8))) short bf16x8;
typedef __attribute__((ext_vector_type(4))) float f32x4;
typedef __attribute__((ext_vector_type(4))) int   i32x4;

static __device__ __forceinline__ u16 f2bf(float f) {
  u32 u = __float_as_uint(f);
  u32 r = (u + 0x7FFFu + ((u >> 16) & 1u)) >> 16;   // RNE
  return (u16)r;
}
static __device__ __forceinline__ float bf2f(u16 u) {
  return __uint_as_float(((u32)u) << 16);
}
static __device__ __forceinline__ u32 cvt_pk_bf16(float lo, float hi) {
  u32 r;
  asm("v_cvt_pk_bf16_f32 %0, %1, %2" : "=v"(r) : "v"(lo), "v"(hi));
  return r;
}

#define GLL16(g, l) __builtin_amdgcn_global_load_lds( \
    (const __attribute__((address_space(1))) u32*)(g), \
    (__attribute__((address_space(3))) u32*)(l), 16, 0, 0)

// ---------------- cast fp32 -> bf16 (4 elems/thread) ----------------
__global__ void cast_kernel(const float* __restrict__ in, u16* __restrict__ out, int n4) {
  int i = blockIdx.x * 256 + threadIdx.x;
  if (i >= n4) return;
  float4 v = ((const float4*)in)[i];
  ushort4 o;
  o.x = f2bf(v.x); o.y = f2bf(v.y); o.z = f2bf(v.z); o.w = f2bf(v.w);
  ((ushort4*)out)[i] = o;
}

// ---------------- RoPE sin/cos table [T][32] ----------------
__global__ void rope_table(float* __restrict__ sT, float* __restrict__ cT) {
  int i = blockIdx.x * 256 + threadIdx.x;   // t*32 + j
  int t = i >> 5, j = i & 31;
  float inv = exp2f((float)j * (-13.287712379549449f / 32.0f)); // 10000^(-j/32)
  float ang = (float)t * inv;
  sT[i] = sinf(ang);
  cT[i] = cosf(ang);
}

// ---------------- GEMM C[M,N] = A[M,K] * B[N,K]^T (bf16 in, fp32 acc) --------
// m97 structure: 128x128 tile, BK=32, 4 waves (2x2 of 64x64), global_load_lds w=16
// XCD-bijective block swizzle (T1): launch with (gridDim.x*gridDim.y) % 8 == 0.
template<int WRITE_BF16>
__global__ __launch_bounds__(256) void gemm_bt(const u16* __restrict__ A,
                                               const u16* __restrict__ B,
                                               void* __restrict__ Cout,
                                               int M, int N, int K)
{
  __shared__ __align__(16) u16 As[128 * 32];
  __shared__ __align__(16) u16 Bs[128 * 32];
  const int tid  = threadIdx.x;
  const int wave = tid >> 6, lane = tid & 63;
  const int l15  = lane & 15, lh = lane >> 4;
  const int wr   = wave >> 1, wc = wave & 1;

  const int nwg = gridDim.x * gridDim.y;
  int lin = blockIdx.y * gridDim.x + blockIdx.x;
  lin = (lin & 7) * (nwg >> 3) + (lin >> 3);          // nwg % 8 == 0
  const size_t bm = (size_t)(lin / gridDim.x);
  const size_t bn = (size_t)(lin % gridDim.x);

  f32x4 acc[4][4] = {};

  const u16* Ab = A + bm * 128 * (size_t)K;
  const u16* Bb = B + bn * 128 * (size_t)K;

  for (int k0 = 0; k0 < K; k0 += 32) {
    __syncthreads();
#pragma unroll
    for (int j = 0; j < 2; ++j) {
      const int ch = j * 4 + wave;            // 8 chunks of 1024B per tile
      const int e  = ch * 512 + lane * 8;     // element within tile (row-major [128][32])
      const int r  = e >> 5, c = e & 31;
      GLL16(Ab + (size_t)r * K + k0 + c, As + ch * 512);
      GLL16(Bb + (size_t)r * K + k0 + c, Bs + ch * 512);
    }
    asm volatile("s_waitcnt vmcnt(0)" ::: "memory");
    __syncthreads();

    bf16x8 af[4], bfr[4];
#pragma unroll
    for (int m = 0; m < 4; ++m)
      af[m] = *(const bf16x8*)(As + (wr * 64 + m * 16 + l15) * 32 + lh * 8);
#pragma unroll
    for (int n = 0; n < 4; ++n)
      bfr[n] = *(const bf16x8*)(Bs + (wc * 64 + n * 16 + l15) * 32 + lh * 8);
#pragma unroll
    for (int m = 0; m < 4; ++m)
#pragma unroll
      for (int n = 0; n < 4; ++n)
        acc[m][n] = __builtin_amdgcn_mfma_f32_16x16x32_bf16(af[m], bfr[n], acc[m][n], 0, 0, 0);
  }

#pragma unroll
  for (int m = 0; m < 4; ++m)
#pragma unroll
    for (int n = 0; n < 4; ++n)
#pragma unroll
      for (int r = 0; r < 4; ++r) {
        size_t row = bm * 128 + wr * 64 + m * 16 + lh * 4 + r;
        size_t col = bn * 128 + wc * 64 + n * 16 + l15;
        float v = acc[m][n][r];
        if (WRITE_BF16) ((u16*)Cout)[row * N + col] = f2bf(v);
        else            ((float*)Cout)[row * N + col] = v;
      }
}

// ---------------- RoPE + head-split + V transpose ----------------
// qkv [T][3072] bf16 -> Q[H][T][64] (roped, *0.125*log2e), K[H][T][64] (roped),
// Vt[H][64][T]
__global__ void rope_reorg(const u16* __restrict__ qkv,
                           const float* __restrict__ sT, const float* __restrict__ cT,
                           u16* __restrict__ Qo, u16* __restrict__ Ko, u16* __restrict__ Vo)
{
  int idx = blockIdx.x * 256 + threadIdx.x;   // (t*16 + h)*32 + j
  int j = idx & 31;
  int h = (idx >> 5) & 15;
  int t = idx >> 9;
  const float QSC = 0.125f * 1.4426950408889634f;  // 1/sqrt(64) * log2(e)
  float s = sT[t * 32 + j], c = cT[t * 32 + j];
  const u16* row = qkv + (size_t)t * NQKV + h * HD;
  float q1 = bf2f(row[j]),          q2 = bf2f(row[j + 32]);
  float k1 = bf2f(row[DM + j]),     k2 = bf2f(row[DM + j + 32]);
  size_t b = ((size_t)h * TSEQ + t) * HD;
  Qo[b + j]      = f2bf((q1 * c - q2 * s) * QSC);
  Qo[b + j + 32] = f2bf((q2 * c + q1 * s) * QSC);
  Ko[b + j]      = f2bf(k1 * c - k2 * s);
  Ko[b + j + 32] = f2bf(k2 * c + k1 * s);
  Vo[((size_t)h * HD + j) * TSEQ + t]      = row[2 * DM + j];
  Vo[((size_t)h * HD + j + 32) * TSEQ + t] = row[2 * DM + j + 32];
}

// ---------------- causal flash attention ----------------
// grid: NH * 32; block handles q-tiles {p, 63-p} -> uniform 65 kv-tile-steps.
// 4 waves x 16 q rows. S^T = mfma(K,Q) so softmax is in-lane (q = lane&15).
__global__ __launch_bounds__(256) void fattn(const u16* __restrict__ Q,
                                             const u16* __restrict__ Kk,
                                             const u16* __restrict__ Vt,
                                             u16* __restrict__ Oa)
{
  __shared__ __align__(16) u16 Ks[64 * 64];
  __shared__ __align__(16) u16 Vs[64 * 64];
  __shared__ __align__(16) u16 Ps[4 * 16 * 64];

  const int h  = blockIdx.x & (NH - 1);
  const int pr = blockIdx.x >> 4;            // 0..31
  const int tid = threadIdx.x;
  const int wave = tid >> 6, lane = tid & 63;
  const int l15 = lane & 15, lh = lane >> 4;

  // staging coords: thread covers rows {tid>>3, +32}, 16B column chunk tid&7
  const int srow0 = tid >> 3;
  const int scb   = tid & 7;
  const size_t kbase = (size_t)h * TSEQ * HD;

  i32x4 kreg[2], vreg[2];

  for (int ph = 0; ph < 2; ++ph) {
    const int qt = ph ? (63 - pr) : pr;
    const int q0 = qt * 64;
    const int nkv = qt + 1;

    // prefetch kv tile 0 into regs
#pragma unroll
    for (int cc = 0; cc < 2; ++cc) {
      int row = srow0 + cc * 32;
      kreg[cc] = *(const i32x4*)(Kk + kbase + (size_t)row * HD + scb * 8);
      vreg[cc] = *(const i32x4*)(Vt + kbase + (size_t)row * TSEQ + scb * 8);
    }

    bf16x8 qf0, qf1;
    {
      const u16* qp = Q + kbase + (size_t)(q0 + wave * 16 + l15) * HD + lh * 8;
      qf0 = *(const bf16x8*)(qp);
      qf1 = *(const bf16x8*)(qp + 32);
    }
    f32x4 oacc[4] = {};
    float mrun = -3.0e38f, lrun = 0.f;

    for (int kt = 0; kt < nkv; ++kt) {
      const int kv0 = kt * 64;
      __syncthreads();                     // prev PV reads of Ks/Vs done
#pragma unroll
      for (int cc = 0; cc < 2; ++cc) {
        int row = srow0 + cc * 32;
        *(i32x4*)(Ks + row * 64 + ((scb ^ (row & 7)) * 8)) = kreg[cc];
        *(i32x4*)(Vs + row * 64 + ((scb ^ (row & 7)) * 8)) = vreg[cc];
      }
      __syncthreads();
      if (kt + 1 < nkv) {                  // prefetch next tile (flight covers QK+softmax)
        const int nv0 = kv0 + 64;
#pragma unroll
        for (int cc = 0; cc < 2; ++cc) {
          int row = srow0 + cc * 32;
          kreg[cc] = *(const i32x4*)(Kk + kbase + (size_t)(nv0 + row) * HD + scb * 8);
          vreg[cc] = *(const i32x4*)(Vt + kbase + (size_t)row * TSEQ + nv0 + scb * 8);
        }
      }

      // S^T: sacc[n][r] = S[kv = n*16+lh*4+r][q = l15]  (log2 domain)
      f32x4 sacc[4];
      __builtin_amdgcn_s_setprio(1);
#pragma unroll
      for (int n = 0; n < 4; ++n) {
        int krow = n * 16 + l15;
        bf16x8 kf0 = *(const bf16x8*)(Ks + krow * 64 + ((lh       ^ (krow & 7)) * 8));
        bf16x8 kf1 = *(const bf16x8*)(Ks + krow * 64 + (((4 + lh) ^ (krow & 7)) * 8));
        f32x4 z = {0.f, 0.f, 0.f, 0.f};
        sacc[n] = __builtin_amdgcn_mfma_f32_16x16x32_bf16(kf0, qf0, z, 0, 0, 0);
        sacc[n] = __builtin_amdgcn_mfma_f32_16x16x32_bf16(kf1, qf1, sacc[n], 0, 0, 0);
      }
      __builtin_amdgcn_s_setprio(0);

      if (kv0 == q0) {                     // diagonal tile: mask kv > q (local coords)
        const int qg = wave * 16 + l15;
#pragma unroll
        for (int n = 0; n < 4; ++n)
#pragma unroll
          for (int r = 0; r < 4; ++r)
            if (n * 16 + lh * 4 + r > qg) sacc[n][r] = -3.0e38f;
      }

      // in-lane max over 16, then 2 shfl across lh groups
      float tm = fmaxf(fmaxf(sacc[0][0], sacc[0][1]), fmaxf(sacc[0][2], sacc[0][3]));
#pragma unroll
      for (int n = 1; n < 4; ++n)
        tm = fmaxf(tm, fmaxf(fmaxf(sacc[n][0], sacc[n][1]), fmaxf(sacc[n][2], sacc[n][3])));
      tm = fmaxf(tm, __shfl_xor(tm, 16));
      tm = fmaxf(tm, __shfl_xor(tm, 32));
      float nm = fmaxf(mrun, tm);
      float sf = exp2f(mrun - nm);
      float rs = 0.f;
#pragma unroll
      for (int n = 0; n < 4; ++n) {
        float p0 = exp2f(sacc[n][0] - nm);
        float p1 = exp2f(sacc[n][1] - nm);
        float p2 = exp2f(sacc[n][2] - nm);
        float p3 = exp2f(sacc[n][3] - nm);
        rs += (p0 + p1) + (p2 + p3);
        uint2 wv;
        wv.x = cvt_pk_bf16(p0, p1);
        wv.y = cvt_pk_bf16(p2, p3);
        // P[q=l15][kv=n*16+lh*4+(0..3)], 16B-chunk XOR swizzle on q
        *(uint2*)(Ps + wave * 1024 + l15 * 64 +
                  (((2 * n + (lh >> 1)) ^ (l15 & 7)) * 8) + (lh & 1) * 4) = wv;
      }
      rs += __shfl_xor(rs, 16);
      rs += __shfl_xor(rs, 32);
      lrun = lrun * sf + rs;
      mrun = nm;

      // redistribute sf to O-layout rows (O row q = lh*4+r, sf lives at lane q)
      float sfr[4];
#pragma unroll
      for (int r = 0; r < 4; ++r) sfr[r] = __shfl(sf, lh * 4 + r);
#pragma unroll
      for (int dn = 0; dn < 4; ++dn)
#pragma unroll
        for (int r = 0; r < 4; ++r) oacc[dn][r] *= sfr[r];

      // PV: O[q][d] += P[q][kv] * V^T[d][kv]   (P wave-private: no barrier needed)
      __builtin_amdgcn_s_setprio(1);
#pragma unroll
      for (int kk = 0; kk < 2; ++kk) {
        bf16x8 pf = *(const bf16x8*)(Ps + wave * 1024 + l15 * 64 +
                                     (((kk * 4 + lh) ^ (l15 & 7)) * 8));
#pragma unroll
        for (int dn = 0; dn < 4; ++dn) {
          int vrow = dn * 16 + l15;
          bf16x8 vf = *(const bf16x8*)(Vs + vrow * 64 + (((kk * 4 + lh) ^ (vrow & 7)) * 8));
          oacc[dn] = __builtin_amdgcn_mfma_f32_16x16x32_bf16(pf, vf, oacc[dn], 0, 0, 0);
        }
      }
      __builtin_amdgcn_s_setprio(0);
    }

    // epilogue: gather l for O rows, normalize, store
    float lr[4];
#pragma unroll
    for (int r = 0; r < 4; ++r) lr[r] = __shfl(lrun, lh * 4 + r);
#pragma unroll
    for (int r = 0; r < 4; ++r) {
      float inv = 1.f / lr[r];
      size_t row = q0 + wave * 16 + lh * 4 + r;
#pragma unroll
      for (int dn = 0; dn < 4; ++dn)
        Oa[row * DM + h * HD + dn * 16 + l15] = f2bf(oacc[dn][r] * inv);
    }
  }
}

extern "C" void kernel_launch(void* const* d_in, const int* in_sizes, int n_in,
                              void* d_out, int out_size, void* d_ws, size_t ws_size,
                              hipStream_t stream)
{
  const float* x     = (const float*)d_in[0];
  const float* wqkv  = (const float*)d_in[1];
  const float* wproj = (const float*)d_in[2];
  float* out = (float*)d_out;

  char* ws = (char*)d_ws;
  size_t off = 0;
  u16* xb   = (u16*)(ws + off); off += (size_t)TSEQ * DM * 2;
  u16* wqb  = (u16*)(ws + off); off += (size_t)NQKV * DM * 2;
  u16* wpb  = (u16*)(ws + off); off += (size_t)DM * DM * 2;
  u16* qkvb = (u16*)(ws + off); off += (size_t)TSEQ * NQKV * 2;
  u16* Qb   = (u16*)(ws + off); off += (size_t)NH * TSEQ * HD * 2;
  u16* Kb   = (u16*)(ws + off); off += (size_t)NH * TSEQ * HD * 2;
  u16* Vb   = (u16*)(ws + off); off += (size_t)NH * TSEQ * HD * 2;
  u16* Ob   = (u16*)(ws + off); off += (size_t)TSEQ * DM * 2;
  float* sT = (float*)(ws + off); off += (size_t)TSEQ * 32 * 4;
  float* cT = (float*)(ws + off); off += (size_t)TSEQ * 32 * 4;

  cast_kernel<<<(TSEQ * DM / 4) / 256, 256, 0, stream>>>(x, xb, TSEQ * DM / 4);
  cast_kernel<<<(NQKV * DM / 4) / 256, 256, 0, stream>>>(wqkv, wqb, NQKV * DM / 4);
  cast_kernel<<<(DM * DM / 4) / 256, 256, 0, stream>>>(wproj, wpb, DM * DM / 4);
  rope_table<<<(TSEQ * 32) / 256, 256, 0, stream>>>(sT, cT);

  gemm_bt<1><<<dim3(NQKV / 128, TSEQ / 128), 256, 0, stream>>>(xb, wqb, qkvb, TSEQ, NQKV, DM);

  rope_reorg<<<(TSEQ * NH * 32) / 256, 256, 0, stream>>>(qkvb, sT, cT, Qb, Kb, Vb);

  fattn<<<NH * 32, 256, 0, stream>>>(Qb, Kb, Vb, Ob);

  gemm_bt<0><<<dim3(DM / 128, TSEQ / 128), 256, 0, stream>>>(Ob, wpb, out, TSEQ, DM, DM);
}

// Round 3
// 178.785 us; speedup vs baseline: 1.3548x; 1.1406x over previous
//
#include <hip/hip_runtime.h>
#include <hip/hip_bf16.h>
#include <stdint.h>

#define TSEQ 4096
#define DM   1024
#define NH   16
#define HD   64
#define NQKV 3072

typedef unsigned short u16;
typedef unsigned int   u32;
typedef __attribute__((ext_vector_type(8))) short bf16x8;
typedef __attribute__((ext_vector_type(4))) float f32x4;
typedef __attribute__((ext_vector_type(4))) int   i32x4;

static __device__ __forceinline__ u16 f2bf(float f) {
  u32 u = __float_as_uint(f);
  u32 r = (u + 0x7FFFu + ((u >> 16) & 1u)) >> 16;   // RNE
  return (u16)r;
}
static __device__ __forceinline__ float bf2f(u16 u) {
  return __uint_as_float(((u32)u) << 16);
}
static __device__ __forceinline__ u32 cvt_pk_bf16(float lo, float hi) {
  u32 r;
  asm("v_cvt_pk_bf16_f32 %0, %1, %2" : "=v"(r) : "v"(lo), "v"(hi));
  return r;
}

#define GLL16(g, l) __builtin_amdgcn_global_load_lds( \
    (const __attribute__((address_space(1))) u32*)(g), \
    (__attribute__((address_space(3))) u32*)(l), 16, 0, 0)

// ---------------- cast fp32 -> bf16 (4 elems/thread) ----------------
__global__ void cast_kernel(const float* __restrict__ in, u16* __restrict__ out, int n4) {
  int i = blockIdx.x * 256 + threadIdx.x;
  if (i >= n4) return;
  float4 v = ((const float4*)in)[i];
  ushort4 o;
  o.x = f2bf(v.x); o.y = f2bf(v.y); o.z = f2bf(v.z); o.w = f2bf(v.w);
  ((ushort4*)out)[i] = o;
}

// ---------------- RoPE sin/cos table [T][32] ----------------
__global__ void rope_table(float* __restrict__ sT, float* __restrict__ cT) {
  int i = blockIdx.x * 256 + threadIdx.x;   // t*32 + j
  int t = i >> 5, j = i & 31;
  float inv = exp2f((float)j * (-13.287712379549449f / 32.0f)); // 10000^(-j/32)
  float ang = (float)t * inv;
  sT[i] = sinf(ang);
  cT[i] = cosf(ang);
}

// ---------------- GEMM C[M,N] = A[M,K] * B[N,K]^T (bf16 in, fp32 acc) --------
// m97 structure: 128x128 tile, BK=32, 4 waves (2x2 of 64x64), global_load_lds w=16
// XCD-bijective block swizzle (T1): launch with (gridDim.x*gridDim.y) % 8 == 0.
template<int WRITE_BF16>
__global__ __launch_bounds__(256) void gemm_bt(const u16* __restrict__ A,
                                               const u16* __restrict__ B,
                                               void* __restrict__ Cout,
                                               int M, int N, int K)
{
  __shared__ __align__(16) u16 As[128 * 32];
  __shared__ __align__(16) u16 Bs[128 * 32];
  const int tid  = threadIdx.x;
  const int wave = tid >> 6, lane = tid & 63;
  const int l15  = lane & 15, lh = lane >> 4;
  const int wr   = wave >> 1, wc = wave & 1;

  const int nwg = gridDim.x * gridDim.y;
  int lin = blockIdx.y * gridDim.x + blockIdx.x;
  lin = (lin & 7) * (nwg >> 3) + (lin >> 3);          // nwg % 8 == 0
  const size_t bm = (size_t)(lin / gridDim.x);
  const size_t bn = (size_t)(lin % gridDim.x);

  f32x4 acc[4][4] = {};

  const u16* Ab = A + bm * 128 * (size_t)K;
  const u16* Bb = B + bn * 128 * (size_t)K;

  for (int k0 = 0; k0 < K; k0 += 32) {
    __syncthreads();
#pragma unroll
    for (int j = 0; j < 2; ++j) {
      const int ch = j * 4 + wave;            // 8 chunks of 1024B per tile
      const int e  = ch * 512 + lane * 8;     // element within tile (row-major [128][32])
      const int r  = e >> 5, c = e & 31;
      GLL16(Ab + (size_t)r * K + k0 + c, As + ch * 512);
      GLL16(Bb + (size_t)r * K + k0 + c, Bs + ch * 512);
    }
    asm volatile("s_waitcnt vmcnt(0)" ::: "memory");
    __syncthreads();

    bf16x8 af[4], bfr[4];
#pragma unroll
    for (int m = 0; m < 4; ++m)
      af[m] = *(const bf16x8*)(As + (wr * 64 + m * 16 + l15) * 32 + lh * 8);
#pragma unroll
    for (int n = 0; n < 4; ++n)
      bfr[n] = *(const bf16x8*)(Bs + (wc * 64 + n * 16 + l15) * 32 + lh * 8);
#pragma unroll
    for (int m = 0; m < 4; ++m)
#pragma unroll
      for (int n = 0; n < 4; ++n)
        acc[m][n] = __builtin_amdgcn_mfma_f32_16x16x32_bf16(af[m], bfr[n], acc[m][n], 0, 0, 0);
  }

#pragma unroll
  for (int m = 0; m < 4; ++m)
#pragma unroll
    for (int n = 0; n < 4; ++n)
#pragma unroll
      for (int r = 0; r < 4; ++r) {
        size_t row = bm * 128 + wr * 64 + m * 16 + lh * 4 + r;
        size_t col = bn * 128 + wc * 64 + n * 16 + l15;
        float v = acc[m][n][r];
        if (WRITE_BF16) ((u16*)Cout)[row * N + col] = f2bf(v);
        else            ((float*)Cout)[row * N + col] = v;
      }
}

// ---------------- RoPE + head-split + V transpose ----------------
// qkv [T][3072] bf16 -> Q[H][T][64] (roped, *0.125*log2e), K[H][T][64] (roped),
// Vt[H][64][T]
__global__ void rope_reorg(const u16* __restrict__ qkv,
                           const float* __restrict__ sT, const float* __restrict__ cT,
                           u16* __restrict__ Qo, u16* __restrict__ Ko, u16* __restrict__ Vo)
{
  int idx = blockIdx.x * 256 + threadIdx.x;   // (t*16 + h)*32 + j
  int j = idx & 31;
  int h = (idx >> 5) & 15;
  int t = idx >> 9;
  const float QSC = 0.125f * 1.4426950408889634f;  // 1/sqrt(64) * log2(e)
  float s = sT[t * 32 + j], c = cT[t * 32 + j];
  const u16* row = qkv + (size_t)t * NQKV + h * HD;
  float q1 = bf2f(row[j]),          q2 = bf2f(row[j + 32]);
  float k1 = bf2f(row[DM + j]),     k2 = bf2f(row[DM + j + 32]);
  size_t b = ((size_t)h * TSEQ + t) * HD;
  Qo[b + j]      = f2bf((q1 * c - q2 * s) * QSC);
  Qo[b + j + 32] = f2bf((q2 * c + q1 * s) * QSC);
  Ko[b + j]      = f2bf(k1 * c - k2 * s);
  Ko[b + j + 32] = f2bf(k2 * c + k1 * s);
  Vo[((size_t)h * HD + j) * TSEQ + t]      = row[2 * DM + j];
  Vo[((size_t)h * HD + j + 32) * TSEQ + t] = row[2 * DM + j + 32];
}

// ---------------- causal flash attention ----------------
// grid: NH*64 blocks, 1 q-tile (64 rows) each, big tiles dispatched first.
// 4 waves x 16 q rows. S^T = mfma(K,Q): softmax in-lane (q = lane&15).
// O^T = mfma(V,P): accumulator shares the q=lane&15 layout -> no sf shuffles.
// K/V double-buffered in LDS: ONE barrier per kv-step.
__global__ __launch_bounds__(256, 4) void fattn(const u16* __restrict__ Q,
                                                const u16* __restrict__ Kk,
                                                const u16* __restrict__ Vt,
                                                u16* __restrict__ Oa)
{
  __shared__ __align__(16) u16 Ks[2][64 * 64];
  __shared__ __align__(16) u16 Vs[2][64 * 64];
  __shared__ __align__(16) u16 Ps[4 * 16 * 64];

  const int h  = blockIdx.x & (NH - 1);
  const int qt = 63 - (blockIdx.x >> 4);
  const int q0 = qt * 64;
  const int nkv = qt + 1;
  const int tid = threadIdx.x;
  const int wave = tid >> 6, lane = tid & 63;
  const int l15 = lane & 15, lh = lane >> 4;
  const int j7  = l15 & 7;
  const int x0  = (lh ^ j7) * 8;             // QK/PV chunk kk=0
  const int x1  = ((4 + lh) ^ j7) * 8;       // chunk kk=1
  const int qg  = wave * 16 + l15;           // q row (local) this lane owns

  // staging coords: thread covers rows {tid>>3, +32}, 16B column chunk tid&7
  const int srow = tid >> 3;
  const int scb  = tid & 7;
  const int soff = srow * 64 + ((scb ^ (srow & 7)) * 8);  // swizzled LDS offset
  const size_t kbase = (size_t)h * TSEQ * HD;

  u16* const pw = Ps + wave * 1024;          // wave-private P region [16][64]
  int pso[4];
#pragma unroll
  for (int n = 0; n < 4; ++n)
    pso[n] = l15 * 64 + (((2 * n + (lh >> 1)) ^ j7) * 8) + (lh & 1) * 4;

  i32x4 kreg[2], vreg[2];
  // tile 0 -> regs -> buf0
#pragma unroll
  for (int cc = 0; cc < 2; ++cc) {
    int row = srow + cc * 32;
    kreg[cc] = *(const i32x4*)(Kk + kbase + (size_t)row * HD + scb * 8);
    vreg[cc] = *(const i32x4*)(Vt + kbase + (size_t)row * TSEQ + scb * 8);
  }
  *(i32x4*)(Ks[0] + soff)             = kreg[0];
  *(i32x4*)(Ks[0] + soff + 32 * 64)   = kreg[1];
  *(i32x4*)(Vs[0] + soff)             = vreg[0];
  *(i32x4*)(Vs[0] + soff + 32 * 64)   = vreg[1];
  if (nkv > 1) {
#pragma unroll
    for (int cc = 0; cc < 2; ++cc) {
      int row = srow + cc * 32;
      kreg[cc] = *(const i32x4*)(Kk + kbase + (size_t)(64 + row) * HD + scb * 8);
      vreg[cc] = *(const i32x4*)(Vt + kbase + (size_t)row * TSEQ + 64 + scb * 8);
    }
  }

  bf16x8 qf0, qf1;
  {
    const u16* qp = Q + kbase + (size_t)(q0 + qg) * HD + lh * 8;
    qf0 = *(const bf16x8*)(qp);
    qf1 = *(const bf16x8*)(qp + 32);
  }
  f32x4 oacc[4] = {};
  float mrun = -3.0e38f, lrun = 0.f;

  __syncthreads();

  for (int kt = 0; kt < nkv; ++kt) {
    const u16* kc = Ks[kt & 1];
    const u16* vc = Vs[kt & 1];
    u16* kn = Ks[(kt & 1) ^ 1];
    u16* vn = Vs[(kt & 1) ^ 1];

    // S^T = mfma(K, Q): sacc[n][r] = S[kv = n*16+lh*4+r][q = l15]  (log2 domain)
    f32x4 sacc[4];
    __builtin_amdgcn_s_setprio(1);
#pragma unroll
    for (int n = 0; n < 4; ++n) {
      const u16* kp = kc + (n * 16 + l15) * 64;
      bf16x8 kf0 = *(const bf16x8*)(kp + x0);
      bf16x8 kf1 = *(const bf16x8*)(kp + x1);
      f32x4 z = {0.f, 0.f, 0.f, 0.f};
      sacc[n] = __builtin_amdgcn_mfma_f32_16x16x32_bf16(kf0, qf0, z, 0, 0, 0);
      sacc[n] = __builtin_amdgcn_mfma_f32_16x16x32_bf16(kf1, qf1, sacc[n], 0, 0, 0);
    }
    __builtin_amdgcn_s_setprio(0);

    // write next tile (regs -> other buffer); issue prefetch for kt+2
    if (kt + 1 < nkv) {
      *(i32x4*)(kn + soff)           = kreg[0];
      *(i32x4*)(kn + soff + 32 * 64) = kreg[1];
      *(i32x4*)(vn + soff)           = vreg[0];
      *(i32x4*)(vn + soff + 32 * 64) = vreg[1];
      if (kt + 2 < nkv) {
        const int nv0 = (kt + 2) * 64;
#pragma unroll
        for (int cc = 0; cc < 2; ++cc) {
          int row = srow + cc * 32;
          kreg[cc] = *(const i32x4*)(Kk + kbase + (size_t)(nv0 + row) * HD + scb * 8);
          vreg[cc] = *(const i32x4*)(Vt + kbase + (size_t)row * TSEQ + nv0 + scb * 8);
        }
      }
    }

    if (kt == qt) {                      // diagonal tile: mask kv > q (local)
#pragma unroll
      for (int n = 0; n < 4; ++n)
#pragma unroll
        for (int r = 0; r < 4; ++r)
          if (n * 16 + lh * 4 + r > qg) sacc[n][r] = -3.0e38f;
    }

    // in-lane max over 16 kv, then 2 shfl across lh groups
    float tm = fmaxf(fmaxf(sacc[0][0], sacc[0][1]), fmaxf(sacc[0][2], sacc[0][3]));
#pragma unroll
    for (int n = 1; n < 4; ++n)
      tm = fmaxf(tm, fmaxf(fmaxf(sacc[n][0], sacc[n][1]), fmaxf(sacc[n][2], sacc[n][3])));
    tm = fmaxf(tm, __shfl_xor(tm, 16));
    tm = fmaxf(tm, __shfl_xor(tm, 32));

    // defer-max (T13): only rescale when max grew by > 8 (log2)
    if (!__all(tm <= mrun + 8.0f)) {
      float nm = fmaxf(mrun, tm);
      float sf = exp2f(mrun - nm);
      lrun *= sf;
#pragma unroll
      for (int dn = 0; dn < 4; ++dn)
#pragma unroll
        for (int r = 0; r < 4; ++r) oacc[dn][r] *= sf;
      mrun = nm;
    }

    float rs = 0.f;
#pragma unroll
    for (int n = 0; n < 4; ++n) {
      float p0 = exp2f(sacc[n][0] - mrun);
      float p1 = exp2f(sacc[n][1] - mrun);
      float p2 = exp2f(sacc[n][2] - mrun);
      float p3 = exp2f(sacc[n][3] - mrun);
      rs += (p0 + p1) + (p2 + p3);
      uint2 wv;
      wv.x = cvt_pk_bf16(p0, p1);
      wv.y = cvt_pk_bf16(p2, p3);
      *(uint2*)(pw + pso[n]) = wv;
    }
    rs += __shfl_xor(rs, 16);
    rs += __shfl_xor(rs, 32);
    lrun += rs;

    // O^T += V * P : oacc[dn] holds O^T[d = dn*16+lh*4+r][q = l15]
    __builtin_amdgcn_s_setprio(1);
#pragma unroll
    for (int kk = 0; kk < 2; ++kk) {
      const int xk = kk ? x1 : x0;
      bf16x8 pf = *(const bf16x8*)(pw + l15 * 64 + xk);
#pragma unroll
      for (int dn = 0; dn < 4; ++dn) {
        bf16x8 vf = *(const bf16x8*)(vc + (dn * 16 + l15) * 64 + xk);
        oacc[dn] = __builtin_amdgcn_mfma_f32_16x16x32_bf16(vf, pf, oacc[dn], 0, 0, 0);
      }
    }
    __builtin_amdgcn_s_setprio(0);

    __syncthreads();
  }

  // epilogue: normalize in-lane, transpose via wave-private LDS bounce, store
  {
    float inv = 1.f / lrun;
#pragma unroll
    for (int dn = 0; dn < 4; ++dn)
#pragma unroll
      for (int r = 0; r < 4; ++r) {
        int d = dn * 16 + lh * 4 + r;
        pw[l15 * 64 + ((d + l15 * 8) & 63)] = f2bf(oacc[dn][r] * inv);
      }
    asm volatile("s_waitcnt lgkmcnt(0)" ::: "memory");
#pragma unroll
    for (int c = 0; c < 2; ++c) {
      int dchunk = (lh + c * 4) * 8;                 // d = lh*8, 32+lh*8
      i32x4 v = *(const i32x4*)(pw + l15 * 64 + ((dchunk + l15 * 8) & 63));
      *(i32x4*)(Oa + (size_t)(q0 + qg) * DM + h * HD + dchunk) = v;
    }
  }
}

extern "C" void kernel_launch(void* const* d_in, const int* in_sizes, int n_in,
                              void* d_out, int out_size, void* d_ws, size_t ws_size,
                              hipStream_t stream)
{
  const float* x     = (const float*)d_in[0];
  const float* wqkv  = (const float*)d_in[1];
  const float* wproj = (const float*)d_in[2];
  float* out = (float*)d_out;

  char* ws = (char*)d_ws;
  size_t off = 0;
  u16* xb   = (u16*)(ws + off); off += (size_t)TSEQ * DM * 2;
  u16* wqb  = (u16*)(ws + off); off += (size_t)NQKV * DM * 2;
  u16* wpb  = (u16*)(ws + off); off += (size_t)DM * DM * 2;
  u16* qkvb = (u16*)(ws + off); off += (size_t)TSEQ * NQKV * 2;
  u16* Qb   = (u16*)(ws + off); off += (size_t)NH * TSEQ * HD * 2;
  u16* Kb   = (u16*)(ws + off); off += (size_t)NH * TSEQ * HD * 2;
  u16* Vb   = (u16*)(ws + off); off += (size_t)NH * TSEQ * HD * 2;
  u16* Ob   = (u16*)(ws + off); off += (size_t)TSEQ * DM * 2;
  float* sT = (float*)(ws + off); off += (size_t)TSEQ * 32 * 4;
  float* cT = (float*)(ws + off); off += (size_t)TSEQ * 32 * 4;

  cast_kernel<<<(TSEQ * DM / 4) / 256, 256, 0, stream>>>(x, xb, TSEQ * DM / 4);
  cast_kernel<<<(NQKV * DM / 4) / 256, 256, 0, stream>>>(wqkv, wqb, NQKV * DM / 4);
  cast_kernel<<<(DM * DM / 4) / 256, 256, 0, stream>>>(wproj, wpb, DM * DM / 4);
  rope_table<<<(TSEQ * 32) / 256, 256, 0, stream>>>(sT, cT);

  gemm_bt<1><<<dim3(NQKV / 128, TSEQ / 128), 256, 0, stream>>>(xb, wqb, qkvb, TSEQ, NQKV, DM);

  rope_reorg<<<(TSEQ * NH * 32) / 256, 256, 0, stream>>>(qkvb, sT, cT, Qb, Kb, Vb);

  fattn<<<NH * 64, 256, 0, stream>>>(Qb, Kb, Vb, Ob);

  gemm_bt<0><<<dim3(DM / 128, TSEQ / 128), 256, 0, stream>>>(Ob, wpb, out, TSEQ, DM, DM);
}